// Round 7
// baseline (1765.360 us; speedup 1.0000x reference)
//
#include <hip/hip_runtime.h>

// Neural-ODE RK4 over MLP 12->300->100->50->12, B=1024, T=100.
// 256 blocks x 512 threads (8 waves), 4 batch elements per block, 1 block/CU.
// 3 barriers per MLP eval:
//   L1 (300 thr, W1 regs) -> A -> L2 (8-way k-split, W2 regs, b128 broadcast
//   reads of transposed h1T) -> B -> wave-local tail (wave e = elem e:
//   h2 reduce + L3 + L4 + RK4 update, in-wave LDS round-trips, no barriers)
//   -> C.
// All weights except W3 in registers; W3 (20KB) LDS chunked conflict-free.

typedef float v2f __attribute__((ext_vector_type(2)));
typedef float v4f __attribute__((ext_vector_type(4)));

constexpr int TT = 100;
constexpr int D  = 12;
constexpr int H1 = 300;
constexpr int H2 = 100;
constexpr int H3 = 50;
constexpr float NEG = 0.01f;

__device__ __forceinline__ float lrelu(float x) { return fmaxf(x, NEG * x); }
__device__ __forceinline__ v2f lo2(v4f v) { return __builtin_shufflevector(v, v, 0, 1); }
__device__ __forceinline__ v2f hi2(v4f v) { return __builtin_shufflevector(v, v, 2, 3); }
__device__ __forceinline__ v2f pkfma(v2f a, v2f b, v2f c) {
#if __has_builtin(__builtin_elementwise_fma)
    return __builtin_elementwise_fma(a, b, c);
#else
    return a * b + c;
#endif
}

__global__ __launch_bounds__(512, 1)
void node_rk4_kernel(const float* __restrict__ y0, const float* __restrict__ t,
                     const float* __restrict__ W1, const float* __restrict__ b1,
                     const float* __restrict__ W2, const float* __restrict__ b2,
                     const float* __restrict__ W3, const float* __restrict__ b3,
                     const float* __restrict__ W4, const float* __restrict__ b4,
                     float* __restrict__ out)
{
    // LDS ~ 41.8 KB
    __shared__ __align__(16) float sW3c[25 * 200];  // [c][j][4k] chunked W3
    __shared__ __align__(16) float h1T [304 * 4];   // [k][e], rows 300-303 zero
    __shared__ __align__(16) float pL2 [32 * 104];  // [(kq8*4+e)][104]
    __shared__ __align__(16) float h2e [4 * 104];   // [e][104]
    __shared__ __align__(16) float h3e [4 * 52];    // [e][52], 50,51 zero
    __shared__ __align__(16) float sx  [48];
    __shared__ __align__(16) float sxe [48];
    __shared__ __align__(16) float sks [48];
    __shared__ float st[104];

    const int tid = threadIdx.x;
    const int l   = tid & 63;
    const int w   = tid >> 6;            // wave 0..7

    // ---- L1: thread j<300 owns col j, 4 elems, W1 in regs ----
    const bool l1act = (tid < H1);
    float w1v[12];
    float rb1 = 0.0f;
#pragma unroll
    for (int k = 0; k < 12; ++k) w1v[k] = 0.0f;
    if (l1act) {
        rb1 = b1[tid];
#pragma unroll
        for (int k = 0; k < 12; ++k) w1v[k] = W1[k * H1 + tid];
    }

    // ---- L2: wave = k-eighth (38 k, padded to 304), lane l<50 owns cols l, l+50 ----
    const bool l2act = (l < 50);
    float w2a[38], w2b[38];
#pragma unroll
    for (int i = 0; i < 38; ++i) {
        const int k = w * 38 + i;
        float va = 0.0f, vb = 0.0f;
        if (l2act && k < H1) { va = W2[k * H2 + l]; vb = W2[k * H2 + l + 50]; }
        w2a[i] = va; w2b[i] = vb;
    }

    // ---- tail: wave e = w (w<4); lane roles ----
    const bool tact = (w < 4);
    float rb2a = 0.f, rb2b = 0.f, rb3 = 0.f;
    if (tact && l < 50) { rb2a = b2[l]; rb2b = b2[l + 50]; rb3 = b3[l]; }
    const int j4  = l >> 2;              // output col for L4 (l<48)
    const int kq4 = l & 3;               // k-quarter for L4
    const bool l4act = tact && (l < 48);
    float w4v[13];
    float b4v = 0.0f;
#pragma unroll
    for (int i = 0; i < 13; ++i) w4v[i] = 0.0f;
    if (l4act) {
        b4v = b4[j4];
#pragma unroll
        for (int i = 0; i < 13; ++i) {
            const int k = kq4 * 13 + i;
            if (k < H3) w4v[i] = W4[k * D + j4];
        }
    }

    // ---- one-time LDS staging ----
    for (int i = tid; i < H2 * H3; i += 512) {      // W3 [k=100][j=50] -> chunked
        const int k = i / H3, j = i - k * H3;
        sW3c[(k >> 2) * 200 + j * 4 + (k & 3)] = W3[i];
    }
    if (tid < 16) h1T[300 * 4 + tid] = 0.0f;        // zero k=300..303
    if (tid >= 16 && tid < 24) {                    // zero h3e pads
        const int u = tid - 16;
        h3e[(u >> 1) * 52 + 50 + (u & 1)] = 0.0f;
    }
    if (tid < TT) st[tid] = t[tid];                 // t row 0
    if (tid < 48) {                                 // x0 = y0[:,0,:]; out[:,0,:]
        const int e = tid / 12, j = tid - e * 12;
        const int g = (blockIdx.x * 4 + e) * (TT * D) + j;
        const float v = y0[g];
        sx[tid] = v;
        out[g]  = v;
    }
    __syncthreads();

    for (int s = 0; s < TT - 1; ++s) {
#pragma unroll 1
        for (int ev = 0; ev < 4; ++ev) {
            const float* xin = ev ? sxe : sx;

            // ===== L1: 12 -> 300, writes h1T[j][0..3] (one b128) =====
            if (l1act) {
                v4f r;
#pragma unroll
                for (int e = 0; e < 4; ++e) {
                    const v4f x0 = *(const v4f*)(xin + e * 12);
                    const v4f x1 = *(const v4f*)(xin + e * 12 + 4);
                    const v4f x2 = *(const v4f*)(xin + e * 12 + 8);
                    float a = rb1;
                    a = fmaf(x0.x, w1v[0], a);  a = fmaf(x0.y, w1v[1], a);
                    a = fmaf(x0.z, w1v[2], a);  a = fmaf(x0.w, w1v[3], a);
                    a = fmaf(x1.x, w1v[4], a);  a = fmaf(x1.y, w1v[5], a);
                    a = fmaf(x1.z, w1v[6], a);  a = fmaf(x1.w, w1v[7], a);
                    a = fmaf(x2.x, w1v[8], a);  a = fmaf(x2.y, w1v[9], a);
                    a = fmaf(x2.z, w1v[10], a); a = fmaf(x2.w, w1v[11], a);
                    r[e] = lrelu(a);
                }
                *(v4f*)(h1T + tid * 4) = r;
            }
            __syncthreads();                        // A: h1T ready

            // ===== L2: 300 -> 100, reg weights, 1 b128 broadcast per k =====
            {
                v2f aA01 = {0,0}, aA23 = {0,0}, aB01 = {0,0}, aB23 = {0,0};
                const float* hb = h1T + w * 38 * 4;
#pragma unroll
                for (int i = 0; i < 38; ++i) {
                    const v4f hv = *(const v4f*)(hb + i * 4);   // elems 0..3 at k
                    const v2f wa = {w2a[i], w2a[i]};
                    const v2f wb = {w2b[i], w2b[i]};
                    aA01 = pkfma(lo2(hv), wa, aA01);
                    aA23 = pkfma(hi2(hv), wa, aA23);
                    aB01 = pkfma(lo2(hv), wb, aB01);
                    aB23 = pkfma(hi2(hv), wb, aB23);
                }
                if (l2act) {
                    pL2[(w * 4 + 0) * 104 + l]      = aA01.x;
                    pL2[(w * 4 + 1) * 104 + l]      = aA01.y;
                    pL2[(w * 4 + 2) * 104 + l]      = aA23.x;
                    pL2[(w * 4 + 3) * 104 + l]      = aA23.y;
                    pL2[(w * 4 + 0) * 104 + l + 50] = aB01.x;
                    pL2[(w * 4 + 1) * 104 + l + 50] = aB01.y;
                    pL2[(w * 4 + 2) * 104 + l + 50] = aB23.x;
                    pL2[(w * 4 + 3) * 104 + l + 50] = aB23.y;
                }
            }
            __syncthreads();                        // B: partials ready

            // ===== wave-local tail: wave e = w does elem e completely =====
            if (tact) {
                const int e = w;
                // -- reduce 8 partials -> h2e (in regs + LDS for broadcast) --
                if (l < 50) {
                    float va = rb2a, vb = rb2b;
#pragma unroll
                    for (int q = 0; q < 8; ++q) {
                        va += pL2[(q * 4 + e) * 104 + l];
                        vb += pL2[(q * 4 + e) * 104 + l + 50];
                    }
                    h2e[e * 104 + l]      = lrelu(va);
                    h2e[e * 104 + l + 50] = lrelu(vb);
                }
                // in-wave LDS write->read: compiler emits lgkmcnt, no barrier
                // -- L3: 100 -> 50, col = l, W3 from LDS --
                if (l < 50) {
                    v2f acc = {0,0};
#pragma unroll
                    for (int c = 0; c < 25; ++c) {
                        const v4f wv = *(const v4f*)(sW3c + c * 200 + l * 4);
                        const v4f hv = *(const v4f*)(h2e + e * 104 + c * 4);
                        acc = pkfma(lo2(hv), lo2(wv), acc);
                        acc = pkfma(hi2(hv), hi2(wv), acc);
                    }
                    h3e[e * 52 + l] = lrelu(acc.x + acc.y + rb3);
                }
                // -- L4: 50 -> 12, k-quarter split + shfl, fused RK4 update --
                if (l < 48) {
                    float a = 0.0f;
                    const float* hb3 = h3e + e * 52 + kq4 * 13;
#pragma unroll
                    for (int i = 0; i < 13; ++i)    // pads zero
                        a = fmaf(hb3[i], w4v[i], a);
                    a += __shfl_xor(a, 1);
                    a += __shfl_xor(a, 2);
                    if (kq4 == 0) {
                        a += b4v;
                        const float dt = st[s + 1] - st[s];
                        const int bi = e * 12 + j4;
                        const float xc = sx[bi];
                        if (ev == 0)      { sks[bi] = a;        sxe[bi] = xc + 0.5f * dt * a; }
                        else if (ev == 1) { sks[bi] += 2.f * a; sxe[bi] = xc + 0.5f * dt * a; }
                        else if (ev == 2) { sks[bi] += 2.f * a; sxe[bi] = xc + dt * a; }
                        else {
                            const float xn = xc + dt * (1.0f / 6.0f) * (sks[bi] + a);
                            sx[bi] = xn;
                            out[(blockIdx.x * 4 + e) * (TT * D) + (s + 1) * D + j4] = xn;
                        }
                    }
                }
            }
            __syncthreads();                        // C: state ready
        }
    }
}

extern "C" void kernel_launch(void* const* d_in, const int* in_sizes, int n_in,
                              void* d_out, int out_size, void* d_ws, size_t ws_size,
                              hipStream_t stream) {
    const float* y0 = (const float*)d_in[0];
    const float* t  = (const float*)d_in[1];
    const float* W1 = (const float*)d_in[2];
    const float* b1 = (const float*)d_in[3];
    const float* W2 = (const float*)d_in[4];
    const float* b2 = (const float*)d_in[5];
    const float* W3 = (const float*)d_in[6];
    const float* b3 = (const float*)d_in[7];
    const float* W4 = (const float*)d_in[8];
    const float* b4 = (const float*)d_in[9];
    float* out = (float*)d_out;

    node_rk4_kernel<<<256, 512, 0, stream>>>(y0, t, W1, b1, W2, b2, W3, b3, W4, b4, out);
}

// Round 8
// 1308.409 us; speedup vs baseline: 1.3492x; 1.3492x over previous
//
#include <hip/hip_runtime.h>

// Neural-ODE RK4 over MLP 12->300->100->50->12, B=1024, T=100.
// R8 = R4 skeleton (256 blocks x 512 thr, 4 elems/block, 1 block/CU,
// parallel 5-barrier tail) + R7's L2 (transposed h1T[k][e] -> one b128
// broadcast read per k; packed v_pk_fma_f32). Registers held at R4's
// level (W1 12 + W2 76 = 88 weight regs; W3/W4/biases in LDS) to avoid
// R7's spill (VGPR=128 + 40MB scratch traffic).

typedef float v2f __attribute__((ext_vector_type(2)));
typedef float v4f __attribute__((ext_vector_type(4)));

constexpr int TT = 100;
constexpr int D  = 12;
constexpr int H1 = 300;
constexpr int H2 = 100;
constexpr int H3 = 50;
constexpr float NEG = 0.01f;

__device__ __forceinline__ float lrelu(float x) { return fmaxf(x, NEG * x); }
__device__ __forceinline__ v2f lo2(v4f v) { return __builtin_shufflevector(v, v, 0, 1); }
__device__ __forceinline__ v2f hi2(v4f v) { return __builtin_shufflevector(v, v, 2, 3); }
__device__ __forceinline__ v2f pkfma(v2f a, v2f b, v2f c) {
#if __has_builtin(__builtin_elementwise_fma)
    return __builtin_elementwise_fma(a, b, c);
#else
    return a * b + c;
#endif
}

__global__ __launch_bounds__(512)
void node_rk4_kernel(const float* __restrict__ y0, const float* __restrict__ t,
                     const float* __restrict__ W1, const float* __restrict__ b1,
                     const float* __restrict__ W2, const float* __restrict__ b2,
                     const float* __restrict__ W3, const float* __restrict__ b3,
                     const float* __restrict__ W4, const float* __restrict__ b4,
                     float* __restrict__ out)
{
    // LDS total ~ 44.5 KB
    __shared__ __align__(16) float sW3c[25 * 200];  // [c][j][4k] chunked W3
    __shared__ __align__(16) float sW4 [52 * 12];   // [k][j], rows 50,51 zero
    __shared__ __align__(16) float h1T [304 * 4];   // [k][e], k=300..303 zero
    __shared__ __align__(16) float pL2 [32 * 104];  // [(w*4+e)][104]
    __shared__ __align__(16) float h2e [4 * 104];   // [e][104]
    __shared__ __align__(16) float h3e [4 * 52];    // [e][52], 50,51 zero
    __shared__ __align__(16) float sx  [48];
    __shared__ __align__(16) float sxe [48];
    __shared__ __align__(16) float sks [48];
    __shared__ float sb2[100];
    __shared__ float st [100];

    const int tid = threadIdx.x;
    const int l   = tid & 63;
    const int w   = tid >> 6;            // wave 0..7 = L2 k-eighth
    const bool l2act = (l < 50);

    // ---- W1 in regs: thread j<300 owns col j ----
    const bool l1act = (tid < H1);
    float w1v[12];
    float rb1 = 0.0f;
#pragma unroll
    for (int k = 0; k < 12; ++k) w1v[k] = 0.0f;
    if (l1act) {
        rb1 = b1[tid];
#pragma unroll
        for (int k = 0; k < 12; ++k) w1v[k] = W1[k * H1 + tid];
    }

    // ---- W2 in regs: wave w owns k = w*38 .. w*38+37; lane l owns cols l, l+50 ----
    float w2a[38], w2b[38];
#pragma unroll
    for (int i = 0; i < 38; ++i) {
        const int k = w * 38 + i;
        float va = 0.0f, vb = 0.0f;
        if (l2act && k < H1) { va = W2[k * H2 + l]; vb = W2[k * H2 + l + 50]; }
        w2a[i] = va; w2b[i] = vb;
    }

    // ---- L3 constants (waves 0-3, lanes<50): bias in reg ----
    const float rb3 = (w < 4 && l < 50) ? b3[l] : 0.0f;

    // ---- L4 lane mapping (waves 4-6, 192 threads) ----
    const int u4 = tid - 256;
    const bool l4act = (u4 >= 0 && u4 < 192);
    int e4 = 0, j4 = 0, kq4 = 0;
    float b4v = 0.0f;
    if (l4act) {
        e4 = u4 / 48; const int r = u4 - e4 * 48; j4 = r >> 2; kq4 = r & 3;
        b4v = b4[j4];
    }

    // ---- one-time LDS staging ----
    for (int i = tid; i < H2 * H3; i += 512) {      // W3 [k=100][j=50] -> chunked
        const int k = i / H3, j = i - k * H3;
        sW3c[(k >> 2) * 200 + j * 4 + (k & 3)] = W3[i];
    }
    for (int i = tid; i < 52 * 12; i += 512) sW4[i] = (i < H3 * D) ? W4[i] : 0.0f;
    if (tid < H2) sb2[tid] = b2[tid];
    if (tid < TT) st[tid] = t[tid];                 // t row 0 (uniform over batch)
    if (tid >= 104 && tid < 120) h1T[300 * 4 + (tid - 104)] = 0.0f;  // k=300..303
    if (tid >= 120 && tid < 128) {                  // h3e pads
        const int u = tid - 120;
        h3e[(u >> 1) * 52 + 50 + (u & 1)] = 0.0f;
    }
    if (tid < 48) {                                 // x0 = y0[:,0,:]; out[:,0,:]
        const int e = tid / 12, j = tid - e * 12;
        const int g = (blockIdx.x * 4 + e) * (TT * D) + j;
        const float v = y0[g];
        sx[tid] = v;
        out[g]  = v;
    }
    __syncthreads();

    for (int s = 0; s < TT - 1; ++s) {
#pragma unroll 1
        for (int ev = 0; ev < 4; ++ev) {
            const float* xin = ev ? sxe : sx;

            // ===== L1: 12 -> 300, col = tid, W1 regs, writes h1T[j][0..3] =====
            if (l1act) {
                v4f r;
#pragma unroll
                for (int e = 0; e < 4; ++e) {
                    const v4f x0 = *(const v4f*)(xin + e * 12);
                    const v4f x1 = *(const v4f*)(xin + e * 12 + 4);
                    const v4f x2 = *(const v4f*)(xin + e * 12 + 8);
                    float a = rb1;
                    a = fmaf(x0.x, w1v[0], a);  a = fmaf(x0.y, w1v[1], a);
                    a = fmaf(x0.z, w1v[2], a);  a = fmaf(x0.w, w1v[3], a);
                    a = fmaf(x1.x, w1v[4], a);  a = fmaf(x1.y, w1v[5], a);
                    a = fmaf(x1.z, w1v[6], a);  a = fmaf(x1.w, w1v[7], a);
                    a = fmaf(x2.x, w1v[8], a);  a = fmaf(x2.y, w1v[9], a);
                    a = fmaf(x2.z, w1v[10], a); a = fmaf(x2.w, w1v[11], a);
                    r[e] = lrelu(a);
                }
                *(v4f*)(h1T + tid * 4) = r;
            }
            __syncthreads();                        // A: h1T ready

            // ===== L2: 300 -> 100, reg weights, 1 b128 broadcast per k, packed =====
            {
                v2f a01A = {0,0}, a23A = {0,0}, a01B = {0,0}, a23B = {0,0};
                const float* hb = h1T + w * (38 * 4);
#pragma unroll
                for (int i = 0; i < 38; ++i) {
                    const v4f hv = *(const v4f*)(hb + i * 4);   // elems 0..3 at k
                    const v2f wA = {w2a[i], w2a[i]};
                    const v2f wB = {w2b[i], w2b[i]};
                    a01A = pkfma(lo2(hv), wA, a01A);
                    a23A = pkfma(hi2(hv), wA, a23A);
                    a01B = pkfma(lo2(hv), wB, a01B);
                    a23B = pkfma(hi2(hv), wB, a23B);
                }
                if (l2act) {
                    pL2[(w * 4 + 0) * 104 + l]      = a01A.x;
                    pL2[(w * 4 + 1) * 104 + l]      = a01A.y;
                    pL2[(w * 4 + 2) * 104 + l]      = a23A.x;
                    pL2[(w * 4 + 3) * 104 + l]      = a23A.y;
                    pL2[(w * 4 + 0) * 104 + l + 50] = a01B.x;
                    pL2[(w * 4 + 1) * 104 + l + 50] = a01B.y;
                    pL2[(w * 4 + 2) * 104 + l + 50] = a23B.x;
                    pL2[(w * 4 + 3) * 104 + l + 50] = a23B.y;
                }
            }
            __syncthreads();                        // B: partials ready

            // ===== reduce -> h2 (8 partials), 400 threads =====
            if (tid < 400) {
                const int e = tid / 100, j = tid - e * 100;
                float v = sb2[j];
#pragma unroll
                for (int q = 0; q < 8; ++q) v += pL2[(q * 4 + e) * 104 + j];
                h2e[e * 104 + j] = lrelu(v);
            }
            __syncthreads();                        // C: h2 ready

            // ===== L3: 100 -> 50, waves 0-3 (e = w), LDS W3, packed =====
            if (w < 4 && l2act) {
                v2f acc = {0, 0};
                const float* hb2 = h2e + w * 104;
                const float* wb  = sW3c + l * 4;
#pragma unroll
                for (int c = 0; c < 25; ++c) {
                    const v4f wv = *(const v4f*)(wb + c * 200);
                    const v4f hv = *(const v4f*)(hb2 + c * 4);
                    acc = pkfma(lo2(hv), lo2(wv), acc);
                    acc = pkfma(hi2(hv), hi2(wv), acc);
                }
                h3e[w * 52 + l] = lrelu(acc.x + acc.y + rb3);
            }
            __syncthreads();                        // D: h3 ready

            // ===== L4: 50 -> 12, waves 4-6, shfl reduce, fused RK4 =====
            if (l4act) {
                const int kb = kq4 * 13;
                float a = 0.0f;
                const float* hb3 = h3e + e4 * 52 + kb;
#pragma unroll
                for (int i = 0; i < 13; ++i)        // k<=51: pads are zero
                    a = fmaf(hb3[i], sW4[(kb + i) * 12 + j4], a);
                a += __shfl_xor(a, 1);
                a += __shfl_xor(a, 2);
                if (kq4 == 0) {
                    a += b4v;
                    const float dt = st[s + 1] - st[s];
                    const int bi = e4 * 12 + j4;
                    const float xc = sx[bi];
                    if (ev == 0)      { sks[bi] = a;        sxe[bi] = xc + 0.5f * dt * a; }
                    else if (ev == 1) { sks[bi] += 2.f * a; sxe[bi] = xc + 0.5f * dt * a; }
                    else if (ev == 2) { sks[bi] += 2.f * a; sxe[bi] = xc + dt * a; }
                    else {
                        const float xn = xc + dt * (1.0f / 6.0f) * (sks[bi] + a);
                        sx[bi] = xn;
                        out[(blockIdx.x * 4 + e4) * (TT * D) + (s + 1) * D + j4] = xn;
                    }
                }
            }
            __syncthreads();                        // E: state ready
        }
    }
}

extern "C" void kernel_launch(void* const* d_in, const int* in_sizes, int n_in,
                              void* d_out, int out_size, void* d_ws, size_t ws_size,
                              hipStream_t stream) {
    const float* y0 = (const float*)d_in[0];
    const float* t  = (const float*)d_in[1];
    const float* W1 = (const float*)d_in[2];
    const float* b1 = (const float*)d_in[3];
    const float* W2 = (const float*)d_in[4];
    const float* b2 = (const float*)d_in[5];
    const float* W3 = (const float*)d_in[6];
    const float* b3 = (const float*)d_in[7];
    const float* W4 = (const float*)d_in[8];
    const float* b4 = (const float*)d_in[9];
    float* out = (float*)d_out;

    node_rk4_kernel<<<256, 512, 0, stream>>>(y0, t, W1, b1, W2, b2, W3, b3, W4, b4, out);
}

// Round 9
// 1170.409 us; speedup vs baseline: 1.5083x; 1.1179x over previous
//
#include <hip/hip_runtime.h>

// Neural-ODE RK4 over MLP 12->300->100->50->12, B=1024, T=100.
// 256 blocks x 512 threads (8 waves), 4 batch elements per block, 1 block/CU.
// R9 = R8 (h1T transpose + packed L2) with register pressure cut below the
// 128-VGPR spill line (W1 moved to LDS; named weight regs: W2 76 only) and
// the tail made wave-local (waves 0-3: h2-reduce + L3 with in-wave lgkmcnt,
// no barrier between them). 4 barriers/eval: A(h1T) B(pL2) D(h3) E(state).

typedef float v2f __attribute__((ext_vector_type(2)));
typedef float v4f __attribute__((ext_vector_type(4)));

constexpr int TT = 100;
constexpr int D  = 12;
constexpr int H1 = 300;
constexpr int H2 = 100;
constexpr int H3 = 50;
constexpr float NEG = 0.01f;

__device__ __forceinline__ float lrelu(float x) { return fmaxf(x, NEG * x); }
__device__ __forceinline__ v2f lo2(v4f v) { return __builtin_shufflevector(v, v, 0, 1); }
__device__ __forceinline__ v2f hi2(v4f v) { return __builtin_shufflevector(v, v, 2, 3); }
__device__ __forceinline__ v2f pkfma(v2f a, v2f b, v2f c) {
#if __has_builtin(__builtin_elementwise_fma)
    return __builtin_elementwise_fma(a, b, c);
#else
    return a * b + c;
#endif
}

__global__ __launch_bounds__(512)
void node_rk4_kernel(const float* __restrict__ y0, const float* __restrict__ t,
                     const float* __restrict__ W1, const float* __restrict__ b1,
                     const float* __restrict__ W2, const float* __restrict__ b2,
                     const float* __restrict__ W3, const float* __restrict__ b3,
                     const float* __restrict__ W4, const float* __restrict__ b4,
                     float* __restrict__ out)
{
    // LDS ~ 59 KB
    __shared__ __align__(16) float sW1 [D * H1];    // [k][j] lane-contiguous
    __shared__ __align__(16) float sW3c[25 * 200];  // [c][j][4k] chunked W3
    __shared__ __align__(16) float sW4 [52 * 12];   // [k][j], rows 50,51 zero
    __shared__ __align__(16) float h1T [304 * 4];   // [k][e], k=300..303 zero
    __shared__ __align__(16) float pL2 [32 * 104];  // [(w*4+e)][104]
    __shared__ __align__(16) float h2e [4 * 104];   // [e][104]
    __shared__ __align__(16) float h3e [4 * 52];    // [e][52], 50,51 zero
    __shared__ __align__(16) float sx  [48];
    __shared__ __align__(16) float sxe [48];
    __shared__ __align__(16) float sks [48];
    __shared__ float st [100];

    const int tid = threadIdx.x;
    const int l   = tid & 63;
    const int w   = tid >> 6;            // wave 0..7 = L2 k-eighth
    const bool l2act = (l < 50);

    // ---- L1 bias only in reg (weights come from LDS each eval) ----
    const bool l1act = (tid < H1);
    const float rb1 = l1act ? b1[tid] : 0.0f;

    // ---- W2 in regs: wave w owns k = w*38 .. w*38+37; lane l owns cols l, l+50 ----
    float w2a[38], w2b[38];
#pragma unroll
    for (int i = 0; i < 38; ++i) {
        const int k = w * 38 + i;
        float va = 0.0f, vb = 0.0f;
        if (l2act && k < H1) { va = W2[k * H2 + l]; vb = W2[k * H2 + l + 50]; }
        w2a[i] = va; w2b[i] = vb;
    }

    // ---- tail-wave constants (waves 0-3, lanes<50) ----
    float rb2a = 0.f, rb2b = 0.f, rb3 = 0.f;
    if (w < 4 && l2act) { rb2a = b2[l]; rb2b = b2[l + 50]; rb3 = b3[l]; }

    // ---- L4 lane mapping (waves 4-6, 192 threads) ----
    const int u4 = tid - 256;
    const bool l4act = (u4 >= 0 && u4 < 192);
    int e4 = 0, j4 = 0, kq4 = 0;
    float b4v = 0.0f;
    if (l4act) {
        e4 = u4 / 48; const int r = u4 - e4 * 48; j4 = r >> 2; kq4 = r & 3;
        b4v = b4[j4];
    }

    // ---- one-time LDS staging ----
    for (int i = tid; i < D * H1; i += 512) sW1[i] = W1[i];          // [k][j]
    for (int i = tid; i < H2 * H3; i += 512) {      // W3 [k=100][j=50] -> chunked
        const int k = i / H3, j = i - k * H3;
        sW3c[(k >> 2) * 200 + j * 4 + (k & 3)] = W3[i];
    }
    for (int i = tid; i < 52 * 12; i += 512) sW4[i] = (i < H3 * D) ? W4[i] : 0.0f;
    if (tid < TT) st[tid] = t[tid];                 // t row 0 (uniform over batch)
    if (tid >= 104 && tid < 120) h1T[300 * 4 + (tid - 104)] = 0.0f;  // k=300..303
    if (tid >= 120 && tid < 128) {                  // h3e pads
        const int u = tid - 120;
        h3e[(u >> 1) * 52 + 50 + (u & 1)] = 0.0f;
    }
    if (tid < 48) {                                 // x0 = y0[:,0,:]; out[:,0,:]
        const int e = tid / 12, j = tid - e * 12;
        const int g = (blockIdx.x * 4 + e) * (TT * D) + j;
        const float v = y0[g];
        sx[tid] = v;
        out[g]  = v;
    }
    __syncthreads();

    for (int s = 0; s < TT - 1; ++s) {
#pragma unroll 1
        for (int ev = 0; ev < 4; ++ev) {
            const float* xin = ev ? sxe : sx;

            // ===== L1: 12 -> 300, col = tid, W1 from LDS, writes h1T[j][0..3] =====
            if (l1act) {
                float wv[12];
#pragma unroll
                for (int k = 0; k < 12; ++k) wv[k] = sW1[k * H1 + tid];
                v4f r;
#pragma unroll
                for (int e = 0; e < 4; ++e) {
                    const v4f x0 = *(const v4f*)(xin + e * 12);
                    const v4f x1 = *(const v4f*)(xin + e * 12 + 4);
                    const v4f x2 = *(const v4f*)(xin + e * 12 + 8);
                    float a = rb1;
                    a = fmaf(x0.x, wv[0], a);  a = fmaf(x0.y, wv[1], a);
                    a = fmaf(x0.z, wv[2], a);  a = fmaf(x0.w, wv[3], a);
                    a = fmaf(x1.x, wv[4], a);  a = fmaf(x1.y, wv[5], a);
                    a = fmaf(x1.z, wv[6], a);  a = fmaf(x1.w, wv[7], a);
                    a = fmaf(x2.x, wv[8], a);  a = fmaf(x2.y, wv[9], a);
                    a = fmaf(x2.z, wv[10], a); a = fmaf(x2.w, wv[11], a);
                    r[e] = lrelu(a);
                }
                *(v4f*)(h1T + tid * 4) = r;
            }
            __syncthreads();                        // A: h1T ready

            // ===== L2: 300 -> 100, reg weights, 1 b128 broadcast per k, packed =====
            {
                v2f a01A = {0,0}, a23A = {0,0}, a01B = {0,0}, a23B = {0,0};
                const float* hb = h1T + w * (38 * 4);
#pragma unroll
                for (int i = 0; i < 38; ++i) {
                    const v4f hv = *(const v4f*)(hb + i * 4);   // elems 0..3 at k
                    const v2f wA = {w2a[i], w2a[i]};
                    const v2f wB = {w2b[i], w2b[i]};
                    a01A = pkfma(lo2(hv), wA, a01A);
                    a23A = pkfma(hi2(hv), wA, a23A);
                    a01B = pkfma(lo2(hv), wB, a01B);
                    a23B = pkfma(hi2(hv), wB, a23B);
                }
                if (l2act) {
                    pL2[(w * 4 + 0) * 104 + l]      = a01A.x;
                    pL2[(w * 4 + 1) * 104 + l]      = a01A.y;
                    pL2[(w * 4 + 2) * 104 + l]      = a23A.x;
                    pL2[(w * 4 + 3) * 104 + l]      = a23A.y;
                    pL2[(w * 4 + 0) * 104 + l + 50] = a01B.x;
                    pL2[(w * 4 + 1) * 104 + l + 50] = a01B.y;
                    pL2[(w * 4 + 2) * 104 + l + 50] = a23B.x;
                    pL2[(w * 4 + 3) * 104 + l + 50] = a23B.y;
                }
            }
            __syncthreads();                        // B: pL2 ready

            // ===== wave-local tail: wave e<4 = elem e: reduce + L3, no barrier =====
            if (w < 4 && l2act) {
                const int e = w;
                // reduce 8 partials -> h2e[e][*]
                float va = rb2a, vb = rb2b;
#pragma unroll
                for (int q = 0; q < 8; ++q) {
                    va += pL2[(q * 4 + e) * 104 + l];
                    vb += pL2[(q * 4 + e) * 104 + l + 50];
                }
                h2e[e * 104 + l]      = lrelu(va);
                h2e[e * 104 + l + 50] = lrelu(vb);
                // in-wave LDS write->read (compiler emits lgkmcnt wait)
                v2f acc = {0, 0};
                const float* hb2 = h2e + e * 104;
                const float* wb  = sW3c + l * 4;
#pragma unroll
                for (int c = 0; c < 25; ++c) {
                    const v4f wv = *(const v4f*)(wb + c * 200);
                    const v4f hv = *(const v4f*)(hb2 + c * 4);
                    acc = pkfma(lo2(hv), lo2(wv), acc);
                    acc = pkfma(hi2(hv), hi2(wv), acc);
                }
                h3e[e * 52 + l] = lrelu(acc.x + acc.y + rb3);
            }
            __syncthreads();                        // D: h3 ready

            // ===== L4: 50 -> 12, waves 4-6, shfl reduce, fused RK4 =====
            if (l4act) {
                const int kb = kq4 * 13;
                float a = 0.0f;
                const float* hb3 = h3e + e4 * 52 + kb;
#pragma unroll
                for (int i = 0; i < 13; ++i)        // k<=51: pads are zero
                    a = fmaf(hb3[i], sW4[(kb + i) * 12 + j4], a);
                a += __shfl_xor(a, 1);
                a += __shfl_xor(a, 2);
                if (kq4 == 0) {
                    a += b4v;
                    const float dt = st[s + 1] - st[s];
                    const int bi = e4 * 12 + j4;
                    const float xc = sx[bi];
                    if (ev == 0)      { sks[bi] = a;        sxe[bi] = xc + 0.5f * dt * a; }
                    else if (ev == 1) { sks[bi] += 2.f * a; sxe[bi] = xc + 0.5f * dt * a; }
                    else if (ev == 2) { sks[bi] += 2.f * a; sxe[bi] = xc + dt * a; }
                    else {
                        const float xn = xc + dt * (1.0f / 6.0f) * (sks[bi] + a);
                        sx[bi] = xn;
                        out[(blockIdx.x * 4 + e4) * (TT * D) + (s + 1) * D + j4] = xn;
                    }
                }
            }
            __syncthreads();                        // E: state ready
        }
    }
}

extern "C" void kernel_launch(void* const* d_in, const int* in_sizes, int n_in,
                              void* d_out, int out_size, void* d_ws, size_t ws_size,
                              hipStream_t stream) {
    const float* y0 = (const float*)d_in[0];
    const float* t  = (const float*)d_in[1];
    const float* W1 = (const float*)d_in[2];
    const float* b1 = (const float*)d_in[3];
    const float* W2 = (const float*)d_in[4];
    const float* b2 = (const float*)d_in[5];
    const float* W3 = (const float*)d_in[6];
    const float* b3 = (const float*)d_in[7];
    const float* W4 = (const float*)d_in[8];
    const float* b4 = (const float*)d_in[9];
    float* out = (float*)d_out;

    node_rk4_kernel<<<256, 512, 0, stream>>>(y0, t, W1, b1, W2, b2, W3, b3, W4, b4, out);
}